// Round 3
// baseline (1160.581 us; speedup 1.0000x reference)
//
#include <hip/hip_runtime.h>

// AGNN / GatedGCN layer for MI355X (gfx950).
// v4: edges processed in src-sorted order end-to-end:
//     - k_edge1 gathers e[eid], writes ehat_s LINEARLY by sorted position,
//       hQ gathers get src-locality (~5 distinct rows per 64-edge block).
//     - k_agg reads its contiguous ehat_s segment sequentially (no gather).
//     - BN-e folded into W1' = diag(sce)@W1, b1' = b1 + she@W1 (in k_finalize),
//       so k_edge2's prologue is a plain bf16 tile copy.
// ws layout (bytes):
//   [0)          wt: 8 slots bf16 transposed [n][k] (P,Q,R,U,V,W1,W2,W1') = 262144
//   [262144)     hQ,hR,hU,hV,xb (5 x 25.6MB f32)
//   [128262144)  ehat_s (E*D bf16, 163.84MB, sorted order)
//   [292102144)  statb: esum/esq/nsum/nsq (64KB) + scn/shn/b1p
//   [292171776)  sortb: cnt, offs, eidS, srcS, dstS

#define NN 50000
#define NE 640000
#define D 128

typedef unsigned int uint32;
typedef unsigned short u16;
typedef short bf16x8 __attribute__((ext_vector_type(8)));
typedef float floatx4 __attribute__((ext_vector_type(4)));

__device__ __forceinline__ u16 f2bf(float f) {
  uint32 u = __float_as_uint(f);
  u += 0x7fffu + ((u >> 16) & 1u);
  return (u16)(u >> 16);
}
__device__ __forceinline__ float bfu2f(uint32 lo16) { return __uint_as_float(lo16 << 16); }
__device__ __forceinline__ uint32 pack2(float a, float b) {
  return (uint32)f2bf(a) | ((uint32)f2bf(b) << 16);
}
__device__ __forceinline__ float fsigmoid(float x) {
  return __builtin_amdgcn_rcpf(1.f + __expf(-x));
}

// Half-tile MFMA: Xs [64][136] bf16 (m,k); Ws [64][136] bf16 holding B rows n0..n0+63.
__device__ __forceinline__ void mfma_half(const u16* __restrict__ Xs,
                                          const u16* __restrict__ Ws,
                                          floatx4* __restrict__ acc, int wave, int lane) {
  const int q = lane >> 4, l = lane & 15;
  const u16* ax = Xs + (wave * 16 + l) * 136 + q * 8;
  const u16* bx = Ws + l * 136 + q * 8;
#pragma unroll
  for (int kk = 0; kk < 4; ++kk) {
    bf16x8 a = *(const bf16x8*)(ax + kk * 32);
#pragma unroll
    for (int nt = 0; nt < 4; ++nt) {
      bf16x8 b = *(const bf16x8*)(bx + nt * 16 * 136 + kk * 32);
      acc[nt] = __builtin_amdgcn_mfma_f32_16x16x32_bf16(a, b, acc[nt], 0, 0, 0);
    }
  }
}

// Stage one 64-row half of a transposed-bf16 weight into Ws (8192 u16).
__device__ __forceinline__ void stage_whalf(u16* __restrict__ Ws, const u16* __restrict__ wsrc,
                                            int tid) {
#pragma unroll
  for (int it = 0; it < 4; ++it) {
    int idx = (it * 256 + tid) * 8;
    *(uint4*)(Ws + (idx >> 7) * 136 + (idx & 127)) = *(const uint4*)(wsrc + idx);
  }
}

// K1: convert 7 weights [k][n] f32 -> transposed bf16 [n][k]
__global__ __launch_bounds__(256) void k_wconv(
    const float* __restrict__ Pw, const float* __restrict__ Qw, const float* __restrict__ Rw,
    const float* __restrict__ Uw, const float* __restrict__ Vw, const float* __restrict__ W1,
    const float* __restrict__ W2, u16* __restrict__ wt) {
  int b = blockIdx.x;
  const float* s = (b == 0) ? Pw : (b == 1) ? Qw : (b == 2) ? Rw : (b == 3) ? Uw
                 : (b == 4) ? Vw : (b == 5) ? W1 : W2;
  u16* dstp = wt + b * 16384;
  for (int idx = threadIdx.x; idx < 16384; idx += 256) {
    int k = idx >> 7, n = idx & 127;
    dstp[n * 128 + k] = f2bf(s[idx]);
  }
}

// K2: hQ/hR/hU/hV = h @ {Qw,Rw,Uw,Vw}
__global__ __launch_bounds__(256, 4) void k_node_gemm(
    const float* __restrict__ h, const u16* __restrict__ wt, float* __restrict__ hQ,
    float* __restrict__ hR, float* __restrict__ hU, float* __restrict__ hV) {
  __shared__ u16 Xs[64 * 136];
  __shared__ u16 Ws[64 * 136];
  const int tid = threadIdx.x;
  const int wave = tid >> 6, lane = tid & 63;
  const int q = lane >> 4, l = lane & 15;
  const int row0 = blockIdx.x * 64;

#pragma unroll
  for (int it = 0; it < 8; ++it) {
    int idx = (it * 256 + tid) * 4;
    int r = idx >> 7, c = idx & 127;
    int g = row0 + r;
    float4 v = make_float4(0.f, 0.f, 0.f, 0.f);
    if (g < NN) v = *(const float4*)(h + (size_t)g * D + c);
    uint2 p;
    p.x = pack2(v.x, v.y);
    p.y = pack2(v.z, v.w);
    *(uint2*)(Xs + r * 136 + c) = p;
  }

  float* const outs[4] = {hQ, hR, hU, hV};
#pragma unroll
  for (int wi = 0; wi < 4; ++wi) {
    __syncthreads();  // prior reads of Ws done
    stage_whalf(Ws, wt + (wi + 1) * 16384, tid);
    __syncthreads();
    floatx4 acc[8] = {};
    mfma_half(Xs, Ws, acc, wave, lane);
    __syncthreads();
    stage_whalf(Ws, wt + (wi + 1) * 16384 + 8192, tid);
    __syncthreads();
    mfma_half(Xs, Ws, acc + 4, wave, lane);
    float* outp = outs[wi];
#pragma unroll
    for (int nt = 0; nt < 8; ++nt) {
#pragma unroll
      for (int r = 0; r < 4; ++r) {
        int m = wave * 16 + q * 4 + r;
        int g = row0 + m;
        if (g < NN) outp[(size_t)g * D + nt * 16 + l] = acc[nt][r];
      }
    }
  }
}

// K_hist: histogram of src
__global__ __launch_bounds__(256) void k_hist(const int* __restrict__ src,
                                              int* __restrict__ cnt) {
  int i = blockIdx.x * 256 + threadIdx.x;
  if (i < NE) atomicAdd(&cnt[src[i]], 1);
}

// K_scan: exclusive prefix sum of cnt -> offs. Single block, 1024 threads x 49 elems.
__global__ __launch_bounds__(1024) void k_scan(const int* __restrict__ cnt,
                                               int* __restrict__ offs) {
  __shared__ int part[1024];
  const int t = threadIdx.x;
  const int base = t * 49;
  int s = 0;
#pragma unroll 7
  for (int j = 0; j < 49; ++j) {
    int i = base + j;
    if (i < NN) s += cnt[i];
  }
  part[t] = s;
  __syncthreads();
  for (int d = 1; d < 1024; d <<= 1) {
    int v = (t >= d) ? part[t - d] : 0;
    __syncthreads();
    part[t] += v;
    __syncthreads();
  }
  int run = (t == 0) ? 0 : part[t - 1];
  for (int j = 0; j < 49; ++j) {
    int i = base + j;
    if (i < NN) {
      offs[i] = run;
      run += cnt[i];
    }
  }
}

// K_scatter: SoA sorted arrays. offs[s] is mutated to segment END.
__global__ __launch_bounds__(256) void k_scatter(const int* __restrict__ src,
                                                 const int* __restrict__ dst,
                                                 int* __restrict__ offs,
                                                 int* __restrict__ eidS,
                                                 int* __restrict__ srcS,
                                                 int* __restrict__ dstS) {
  int i = blockIdx.x * 256 + threadIdx.x;
  if (i < NE) {
    int s = src[i], d = dst[i];
    int p = atomicAdd(&offs[s], 1);
    eidS[p] = i;
    srcS[p] = s;
    dstS[p] = d;
  }
}

// K3: over sorted positions: ehat_s[pos] = e[eid]@P + hQ[src] + hR[dst] (bf16, linear
// write); BN-e stats partials. src nearly constant per block -> hQ gathers are L1-hot.
__global__ __launch_bounds__(256, 4) void k_edge1(
    const float* __restrict__ e, const int* __restrict__ eidS, const int* __restrict__ srcS,
    const int* __restrict__ dstS, const u16* __restrict__ wt, const float* __restrict__ hQ,
    const float* __restrict__ hR, u16* __restrict__ ehat_s, float* __restrict__ esum,
    float* __restrict__ esq) {
  __shared__ u16 Xs[64 * 136];
  __shared__ u16 Ws[64 * 136];
  __shared__ int sSrc[64], sDst[64];
  __shared__ float sSum[128], sSq[128];
  const int tid = threadIdx.x;
  const int wave = tid >> 6, lane = tid & 63;
  const int q = lane >> 4, l = lane & 15;
  const int row0 = blockIdx.x * 64;

  if (tid < 128) { sSum[tid] = 0.f; sSq[tid] = 0.f; }
  if (tid < 64) { sSrc[tid] = srcS[row0 + tid]; sDst[tid] = dstS[row0 + tid]; }
#pragma unroll
  for (int it = 0; it < 8; ++it) {
    int idx = (it * 256 + tid) * 4;
    int r = idx >> 7, c = idx & 127;
    int eid = eidS[row0 + r];  // L1-broadcast (8 threads share r)
    float4 v = *(const float4*)(e + (size_t)eid * D + c);
    uint2 p;
    p.x = pack2(v.x, v.y);
    p.y = pack2(v.z, v.w);
    *(uint2*)(Xs + r * 136 + c) = p;
  }
  stage_whalf(Ws, wt, tid);  // Pw rows 0..63
  __syncthreads();

  floatx4 acc[8] = {};
  mfma_half(Xs, Ws, acc, wave, lane);
  __syncthreads();
  stage_whalf(Ws, wt + 8192, tid);  // Pw rows 64..127
  __syncthreads();
  mfma_half(Xs, Ws, acc + 4, wave, lane);

  float cs[8] = {}, cq[8] = {};
#pragma unroll
  for (int nt = 0; nt < 8; ++nt) {
    const int n = nt * 16 + l;
#pragma unroll
    for (int r = 0; r < 4; ++r) {
      const int m = wave * 16 + q * 4 + r;
      const int s = sSrc[m], dd = sDst[m];
      float v = acc[nt][r] + hQ[(size_t)s * D + n] + hR[(size_t)dd * D + n];
      ehat_s[(size_t)(row0 + m) * D + n] = f2bf(v);
      cs[nt] += v;
      cq[nt] += v * v;
    }
  }
#pragma unroll
  for (int nt = 0; nt < 8; ++nt) {
    cs[nt] += __shfl_xor(cs[nt], 16);
    cs[nt] += __shfl_xor(cs[nt], 32);
    cq[nt] += __shfl_xor(cq[nt], 16);
    cq[nt] += __shfl_xor(cq[nt], 32);
    if (q == 0) {
      atomicAdd(&sSum[nt * 16 + l], cs[nt]);
      atomicAdd(&sSq[nt * 16 + l], cq[nt]);
    }
  }
  __syncthreads();
  if (tid < 128) {
    atomicAdd(&esum[(blockIdx.x & 31) * D + tid], sSum[tid]);
    atomicAdd(&esq[(blockIdx.x & 31) * D + tid], sSq[tid]);
  }
}

// K_agg: x = hU + sum_{seg} sigmoid(ehat_s)*hV[dstS], segment CONTIGUOUS in ehat_s.
// 32 lanes per node (float4/lane covers D=128), 8 nodes per 256-thread block.
__global__ __launch_bounds__(256) void k_agg(
    const u16* __restrict__ ehat_s, const float* __restrict__ hV, const float* __restrict__ hU,
    const int* __restrict__ cnt, const int* __restrict__ offs, const int* __restrict__ dstS,
    float* __restrict__ xb, float* __restrict__ nsum, float* __restrict__ nsq) {
  __shared__ float sSum[128], sSq[128];
  const int tid = threadIdx.x;
  if (tid < 128) { sSum[tid] = 0.f; sSq[tid] = 0.f; }
  __syncthreads();
  const int lane = tid & 31;
  const int n = blockIdx.x * 8 + (tid >> 5);  // 6250*8 == NN exactly
  const int end = offs[n];                    // offs advanced to END by k_scatter
  const int deg = cnt[n];
  const int p0 = end - deg;
  const int c4 = lane * 4;
  float4 acc = make_float4(0.f, 0.f, 0.f, 0.f);
  int k = 0;
  for (; k + 4 <= deg; k += 4) {
    int d0 = dstS[p0 + k + 0];
    int d1 = dstS[p0 + k + 1];
    int d2 = dstS[p0 + k + 2];
    int d3 = dstS[p0 + k + 3];
    uint2 ev0 = *(const uint2*)(ehat_s + (size_t)(p0 + k + 0) * D + c4);
    uint2 ev1 = *(const uint2*)(ehat_s + (size_t)(p0 + k + 1) * D + c4);
    uint2 ev2 = *(const uint2*)(ehat_s + (size_t)(p0 + k + 2) * D + c4);
    uint2 ev3 = *(const uint2*)(ehat_s + (size_t)(p0 + k + 3) * D + c4);
    float4 v0 = *(const float4*)(hV + (size_t)d0 * D + c4);
    float4 v1 = *(const float4*)(hV + (size_t)d1 * D + c4);
    float4 v2 = *(const float4*)(hV + (size_t)d2 * D + c4);
    float4 v3 = *(const float4*)(hV + (size_t)d3 * D + c4);
    acc.x += v0.x * fsigmoid(bfu2f(ev0.x & 0xffffu));
    acc.y += v0.y * fsigmoid(bfu2f(ev0.x >> 16));
    acc.z += v0.z * fsigmoid(bfu2f(ev0.y & 0xffffu));
    acc.w += v0.w * fsigmoid(bfu2f(ev0.y >> 16));
    acc.x += v1.x * fsigmoid(bfu2f(ev1.x & 0xffffu));
    acc.y += v1.y * fsigmoid(bfu2f(ev1.x >> 16));
    acc.z += v1.z * fsigmoid(bfu2f(ev1.y & 0xffffu));
    acc.w += v1.w * fsigmoid(bfu2f(ev1.y >> 16));
    acc.x += v2.x * fsigmoid(bfu2f(ev2.x & 0xffffu));
    acc.y += v2.y * fsigmoid(bfu2f(ev2.x >> 16));
    acc.z += v2.z * fsigmoid(bfu2f(ev2.y & 0xffffu));
    acc.w += v2.w * fsigmoid(bfu2f(ev2.y >> 16));
    acc.x += v3.x * fsigmoid(bfu2f(ev3.x & 0xffffu));
    acc.y += v3.y * fsigmoid(bfu2f(ev3.x >> 16));
    acc.z += v3.z * fsigmoid(bfu2f(ev3.y & 0xffffu));
    acc.w += v3.w * fsigmoid(bfu2f(ev3.y >> 16));
  }
  for (; k < deg; ++k) {
    int dd = dstS[p0 + k];
    uint2 ev = *(const uint2*)(ehat_s + (size_t)(p0 + k) * D + c4);
    float4 v = *(const float4*)(hV + (size_t)dd * D + c4);
    acc.x += v.x * fsigmoid(bfu2f(ev.x & 0xffffu));
    acc.y += v.y * fsigmoid(bfu2f(ev.x >> 16));
    acc.z += v.z * fsigmoid(bfu2f(ev.y & 0xffffu));
    acc.w += v.w * fsigmoid(bfu2f(ev.y >> 16));
  }
  float4 u = *(const float4*)(hU + (size_t)n * D + c4);
  float4 x = make_float4(u.x + acc.x, u.y + acc.y, u.z + acc.z, u.w + acc.w);
  *(float4*)(xb + (size_t)n * D + c4) = x;
  atomicAdd(&sSum[c4 + 0], x.x);
  atomicAdd(&sSum[c4 + 1], x.y);
  atomicAdd(&sSum[c4 + 2], x.z);
  atomicAdd(&sSum[c4 + 3], x.w);
  atomicAdd(&sSq[c4 + 0], x.x * x.x);
  atomicAdd(&sSq[c4 + 1], x.y * x.y);
  atomicAdd(&sSq[c4 + 2], x.z * x.z);
  atomicAdd(&sSq[c4 + 3], x.w * x.w);
  __syncthreads();
  if (tid < 128) {
    atomicAdd(&nsum[(blockIdx.x & 31) * D + tid], sSum[tid]);
    atomicAdd(&nsq[(blockIdx.x & 31) * D + tid], sSq[tid]);
  }
}

// K5: finalize both BNs; fold BN-e into W1' (bf16 [n][k] in wt slot 7) and b1'.
__global__ __launch_bounds__(128) void k_finalize(
    const float* __restrict__ esum, const float* __restrict__ esq,
    const float* __restrict__ nsum, const float* __restrict__ nsq,
    const float* __restrict__ ge, const float* __restrict__ be, const float* __restrict__ gn,
    const float* __restrict__ bnb, const float* __restrict__ W1, const float* __restrict__ b1,
    float* __restrict__ scn, float* __restrict__ shn, u16* __restrict__ wt7,
    float* __restrict__ b1p) {
  __shared__ float sSc[128], sSh[128];
  const int t = threadIdx.x;
  float s = 0.f, q = 0.f;
  for (int i = 0; i < 32; ++i) { s += esum[i * D + t]; q += esq[i * D + t]; }
  float mean = s / (float)NE;
  float var = q / (float)NE - mean * mean;
  float istd = rsqrtf(var + 1e-5f);
  float sce = istd * ge[t];
  float she = be[t] - mean * sce;
  sSc[t] = sce;
  sSh[t] = she;
  s = 0.f; q = 0.f;
  for (int i = 0; i < 32; ++i) { s += nsum[i * D + t]; q += nsq[i * D + t]; }
  mean = s / (float)NN;
  var = q / (float)NN - mean * mean;
  istd = rsqrtf(var + 1e-5f);
  scn[t] = istd * gn[t];
  shn[t] = bnb[t] - mean * istd * gn[t];
  __syncthreads();
  // fold: thread t owns output column n=t of W1.
  float acc = b1[t];
  for (int k = 0; k < 128; ++k) {
    float w = W1[k * D + t];           // coalesced across threads
    acc += sSh[k] * w;
    wt7[t * D + k] = f2bf(sSc[k] * w); // W1' transposed [n][k]
  }
  b1p[t] = acc;
}

// K6: oute[eid] = e[eid] + relu(ehat_s@W1' + b1')@W2 + b2  (BN pre-folded)
__global__ __launch_bounds__(256, 4) void k_edge2(
    const u16* __restrict__ ehat_s, const int* __restrict__ eidS, const float* __restrict__ e,
    const u16* __restrict__ wt, const float* __restrict__ b1p, const float* __restrict__ b2,
    float* __restrict__ oute) {
  __shared__ u16 Ts[64 * 136];
  __shared__ u16 Ws[64 * 136];
  __shared__ float sB1[128], sB2[128];
  __shared__ int sEid[64];
  const int tid = threadIdx.x;
  const int wave = tid >> 6, lane = tid & 63;
  const int q = lane >> 4, l = lane & 15;
  const int row0 = blockIdx.x * 64;

  if (tid < 128) { sB1[tid] = b1p[tid]; sB2[tid] = b2[tid]; }
  if (tid < 64) sEid[tid] = eidS[row0 + tid];

#pragma unroll
  for (int it = 0; it < 4; ++it) {
    int idx = (it * 256 + tid) * 8;
    int r = idx >> 7, c = idx & 127;
    *(uint4*)(Ts + r * 136 + c) = *(const uint4*)(ehat_s + (size_t)(row0 + r) * D + c);
  }
  stage_whalf(Ws, wt + 7 * 16384, tid);  // W1' rows 0..63
  __syncthreads();

  floatx4 acc[8] = {};
  mfma_half(Ts, Ws, acc, wave, lane);
  __syncthreads();
  stage_whalf(Ws, wt + 7 * 16384 + 8192, tid);  // W1' rows 64..127
  __syncthreads();
  mfma_half(Ts, Ws, acc + 4, wave, lane);
  __syncthreads();  // all reads of Ts done before overwrite

#pragma unroll
  for (int nt = 0; nt < 8; ++nt) {
    int n = nt * 16 + l;
#pragma unroll
    for (int r = 0; r < 4; ++r) {
      int m = wave * 16 + q * 4 + r;
      float v = acc[nt][r] + sB1[n];
      Ts[m * 136 + n] = f2bf(fmaxf(v, 0.f));
    }
  }
  stage_whalf(Ws, wt + 6 * 16384, tid);  // W2 rows 0..63
  __syncthreads();

  floatx4 acc2[8] = {};
  mfma_half(Ts, Ws, acc2, wave, lane);
  __syncthreads();
  stage_whalf(Ws, wt + 6 * 16384 + 8192, tid);  // W2 rows 64..127
  __syncthreads();
  mfma_half(Ts, Ws, acc2 + 4, wave, lane);

#pragma unroll
  for (int nt = 0; nt < 8; ++nt) {
    int n = nt * 16 + l;
#pragma unroll
    for (int r = 0; r < 4; ++r) {
      int m = wave * 16 + q * 4 + r;
      size_t gi = (size_t)sEid[m] * D + n;
      oute[gi] = e[gi] + acc2[nt][r] + sB2[n];
    }
  }
}

// K7: h_new = h + alpha * (x*scale + shift), x precomputed by k_agg
__global__ __launch_bounds__(256) void k_node_out(
    const float* __restrict__ h, const float* __restrict__ xb,
    const float* __restrict__ scn, const float* __restrict__ shn,
    const float* __restrict__ alphap, float* __restrict__ outh) {
  size_t idx = ((size_t)blockIdx.x * 256 + threadIdx.x) * 4;  // 6250*256*4 == NN*D
  int c = (int)(idx & 127);
  float al = alphap[0];
  float4 x = *(const float4*)(xb + idx);
  float4 hh = *(const float4*)(h + idx);
  float4 o;
  o.x = hh.x + al * (x.x * scn[c + 0] + shn[c + 0]);
  o.y = hh.y + al * (x.y * scn[c + 1] + shn[c + 1]);
  o.z = hh.z + al * (x.z * scn[c + 2] + shn[c + 2]);
  o.w = hh.w + al * (x.w * scn[c + 3] + shn[c + 3]);
  *(float4*)(outh + idx) = o;
}

extern "C" void kernel_launch(void* const* d_in, const int* in_sizes, int n_in, void* d_out,
                              int out_size, void* d_ws, size_t ws_size, hipStream_t stream) {
  const float* h = (const float*)d_in[0];
  const float* e = (const float*)d_in[1];
  const int* ei = (const int*)d_in[2];
  const float* Pw = (const float*)d_in[3];
  const float* Qw = (const float*)d_in[4];
  const float* Rw = (const float*)d_in[5];
  const float* Uw = (const float*)d_in[6];
  const float* Vw = (const float*)d_in[7];
  const float* W1 = (const float*)d_in[8];
  const float* b1 = (const float*)d_in[9];
  const float* W2 = (const float*)d_in[10];
  const float* b2 = (const float*)d_in[11];
  const float* ge = (const float*)d_in[12];
  const float* be = (const float*)d_in[13];
  const float* gn = (const float*)d_in[14];
  const float* bnb = (const float*)d_in[15];
  const float* al = (const float*)d_in[16];

  const int* srcp = ei;
  const int* dstp = ei + NE;

  char* ws = (char*)d_ws;
  u16* wt = (u16*)(ws);  // 8 slots x 32KB = 262144 B
  float* hQ = (float*)(ws + 262144ull);
  float* hR = (float*)(ws + 262144ull + 1ull * 25600000ull);
  float* hU = (float*)(ws + 262144ull + 2ull * 25600000ull);
  float* hV = (float*)(ws + 262144ull + 3ull * 25600000ull);
  float* xb = (float*)(ws + 262144ull + 4ull * 25600000ull);
  u16* ehat = (u16*)(ws + 128262144ull);
  char* statb = ws + 292102144ull;
  float* esum = (float*)(statb);
  float* esq = (float*)(statb + 16384);
  float* nsum = (float*)(statb + 32768);
  float* nsq = (float*)(statb + 49152);
  float* scn = (float*)(statb + 65536);
  float* shn = (float*)(statb + 66048);
  float* b1p = (float*)(statb + 66560);
  char* sortb = ws + 292171776ull;
  int* cnt = (int*)(sortb);
  int* offs = (int*)(sortb + 200704);
  int* eidS = (int*)(sortb + 401408);
  int* srcS = (int*)(sortb + 2961408);
  int* dstS = (int*)(sortb + 5521408);

  float* outh = (float*)d_out;
  float* oute = outh + (size_t)NN * D;

  // one memset: stats (64KB) + scn/shn/b1p (overwritten later anyway) + cnt
  hipMemsetAsync(statb, 0, 69632 + 200704, stream);

  k_wconv<<<7, 256, 0, stream>>>(Pw, Qw, Rw, Uw, Vw, W1, W2, wt);
  k_hist<<<2500, 256, 0, stream>>>(srcp, cnt);
  k_scan<<<1, 1024, 0, stream>>>(cnt, offs);
  k_scatter<<<2500, 256, 0, stream>>>(srcp, dstp, offs, eidS, srcS, dstS);
  k_node_gemm<<<782, 256, 0, stream>>>(h, wt, hQ, hR, hU, hV);
  k_edge1<<<10000, 256, 0, stream>>>(e, eidS, srcS, dstS, wt, hQ, hR, ehat, esum, esq);
  k_agg<<<6250, 256, 0, stream>>>(ehat, hV, hU, cnt, offs, dstS, xb, nsum, nsq);
  k_finalize<<<1, 128, 0, stream>>>(esum, esq, nsum, nsq, ge, be, gn, bnb, W1, b1,
                                    scn, shn, wt + 7 * 16384, b1p);
  k_edge2<<<10000, 256, 0, stream>>>(ehat, eidS, e, wt, b1p, b2, oute);
  k_node_out<<<6250, 256, 0, stream>>>(h, xb, scn, shn, al, outh);
}